// Round 1
// baseline (729.198 us; speedup 1.0000x reference)
//
#include <hip/hip_runtime.h>

#define NN 50000
#define NE 400000

typedef unsigned short u16;
typedef unsigned int   u32;
typedef __bf16 bf16x4 __attribute__((ext_vector_type(4)));
typedef __bf16 bf16x8 __attribute__((ext_vector_type(8)));
typedef float  f32x4  __attribute__((ext_vector_type(4)));

union ABFrag { bf16x8 v; bf16x4 h[2]; };

__device__ __forceinline__ u16 f2bfu(float f) {
  u32 u = __builtin_bit_cast(u32, f);
  return (u16)((u + 0x7FFFu + ((u >> 16) & 1u)) >> 16);  // RNE f32->bf16
}

// ---------------- f32 -> bf16 bulk convert (vec4) ----------------
__global__ __launch_bounds__(256) void k_cvt(const float* __restrict__ src,
                                             u16* __restrict__ dst, int n4) {
  int i = blockIdx.x * 256 + threadIdx.x;
  if (i >= n4) return;
  float4 f = ((const float4*)src)[i];
  ushort4 o;
  o.x = f2bfu(f.x); o.y = f2bfu(f.y); o.z = f2bfu(f.z); o.w = f2bfu(f.w);
  ((ushort4*)dst)[i] = o;
}

// ---------------- weight pack: W[K][256] f32 -> MFMA-fragment order bf16 ----
// pack[((t*256+n)*4+g)*8+j] = W[32t + 4g + (j%4) + 16*(j/4)][n]
// so each lane's 8-elem B fragment is one contiguous 16B LDS read.
__global__ __launch_bounds__(256) void k_pack(const float* __restrict__ W,
                                              u16* __restrict__ P, int K) {
  int idx = blockIdx.x * 256 + threadIdx.x;
  if (idx >= K * 256) return;
  int k = idx >> 8, n = idx & 255;
  int t = k >> 5, kp = k & 31;
  int g = (kp & 15) >> 2;
  int j = (kp & 3) | ((kp >> 4) << 2);
  P[(((t << 8) + n) << 5) + (g << 3) + j] = f2bfu(W[idx]);
}

// ---------------- message GEMM (64 edges x 320 @ 320x256) + atomic scatter ---
__global__ __launch_bounds__(256) void k_msg(
    const u16* __restrict__ nodes_bf, const float* __restrict__ edges,
    const int* __restrict__ senders, const int* __restrict__ receivers,
    const u16* __restrict__ wpack, float* __restrict__ agg)
{
  __shared__ u16 At[64][328];      // 64 edges x K=320 (+8 pad)
  __shared__ u16 Bt[256 * 40];     // one K-step: [n][g][8] (+8 pad per n)
  __shared__ int rcv[64];

  const int tid  = threadIdx.x;
  const int lane = tid & 63;
  const int w    = tid >> 6;
  const int l16  = lane & 15;
  const int g    = lane >> 4;
  const int e0   = blockIdx.x * 64;

  if (tid < 64) rcv[tid] = receivers[e0 + tid];

  // stage A: cols 0..255 gathered from nodes_bf, 256..319 from edges (cvt f32)
  #pragma unroll
  for (int it = 0; it < 10; ++it) {
    int c = tid + it * 256;                 // 2560 chunks of 16B
    int r = c / 40, seg = c - r * 40;
    if (seg < 32) {
      int snd = senders[e0 + r];
      *(uint4*)&At[r][seg * 8] =
          *(const uint4*)(nodes_bf + (size_t)snd * 256 + seg * 8);
    } else {
      const float* src = edges + (size_t)(e0 + r) * 64 + (seg - 32) * 8;
      float4 f0 = ((const float4*)src)[0];
      float4 f1 = ((const float4*)src)[1];
      ushort4 o0, o1;
      o0.x = f2bfu(f0.x); o0.y = f2bfu(f0.y); o0.z = f2bfu(f0.z); o0.w = f2bfu(f0.w);
      o1.x = f2bfu(f1.x); o1.y = f2bfu(f1.y); o1.z = f2bfu(f1.z); o1.w = f2bfu(f1.w);
      *(ushort4*)&At[r][seg * 8]     = o0;
      *(ushort4*)&At[r][seg * 8 + 4] = o1;
    }
  }

  f32x4 acc[4][4];
  const f32x4 z = {0.f, 0.f, 0.f, 0.f};
  #pragma unroll
  for (int i = 0; i < 4; ++i)
    #pragma unroll
    for (int q = 0; q < 4; ++q) acc[i][q] = z;

  for (int t = 0; t < 10; ++t) {
    if (t) __syncthreads();                 // Bt free before overwrite
    #pragma unroll
    for (int it = 0; it < 4; ++it) {
      int c = tid + it * 256;               // 1024 chunks of 16B
      int n = c >> 2, gg = c & 3;
      *(uint4*)&Bt[n * 40 + gg * 8] = *(const uint4*)(wpack + (t << 13) + (c << 3));
    }
    __syncthreads();

    ABFrag a[4];
    const int kb = (t << 5) + (g << 2);
    #pragma unroll
    for (int mf = 0; mf < 4; ++mf) {
      int m = (mf << 4) + l16;
      a[mf].h[0] = *(const bf16x4*)&At[m][kb];
      a[mf].h[1] = *(const bf16x4*)&At[m][kb + 16];
    }
    #pragma unroll
    for (int q = 0; q < 4; ++q) {
      int n = (w << 6) + (q << 4) + l16;
      bf16x8 b = *(const bf16x8*)&Bt[n * 40 + (g << 3)];
      #pragma unroll
      for (int mf = 0; mf < 4; ++mf)
        acc[mf][q] = __builtin_amdgcn_mfma_f32_16x16x32_bf16(a[mf].v, b, acc[mf][q], 0, 0, 0);
    }
  }

  // scatter-add into agg[receiver]
  #pragma unroll
  for (int mf = 0; mf < 4; ++mf) {
    #pragma unroll
    for (int r = 0; r < 4; ++r) {
      int m = (mf << 4) + (g << 2) + r;     // C row = edge index in tile
      size_t base = (size_t)rcv[m] * 256;
      #pragma unroll
      for (int q = 0; q < 4; ++q) {
        int n = (w << 6) + (q << 4) + l16;
        unsafeAtomicAdd(&agg[base + n], acc[mf][q][r]);
      }
    }
  }
}

// ---------------- h = LN(relu(agg) + nodes); write f32 + bf16 ----------------
__global__ __launch_bounds__(256) void k_ln_aggr(
    const float* __restrict__ agg, const float* __restrict__ nodes,
    const float* __restrict__ lns, const float* __restrict__ lnb,
    float* __restrict__ hf, u16* __restrict__ hb)
{
  const int lane = threadIdx.x & 63;
  const size_t row = (size_t)blockIdx.x * 4 + (threadIdx.x >> 6);
  const float4 a4 = ((const float4*)(agg   + row * 256))[lane];
  const float4 n4 = ((const float4*)(nodes + row * 256))[lane];
  float v0 = fmaxf(a4.x, 0.f) + n4.x, v1 = fmaxf(a4.y, 0.f) + n4.y;
  float v2 = fmaxf(a4.z, 0.f) + n4.z, v3 = fmaxf(a4.w, 0.f) + n4.w;
  float s  = v0 + v1 + v2 + v3;
  float s2 = v0 * v0 + v1 * v1 + v2 * v2 + v3 * v3;
  #pragma unroll
  for (int m = 32; m; m >>= 1) { s += __shfl_xor(s, m); s2 += __shfl_xor(s2, m); }
  float mu  = s * (1.f / 256.f);
  float var = s2 * (1.f / 256.f) - mu * mu;
  float rs  = rsqrtf(var + 1e-6f);
  float4 sc = ((const float4*)lns)[lane];
  float4 bi = ((const float4*)lnb)[lane];
  float h0 = (v0 - mu) * rs * sc.x + bi.x;
  float h1 = (v1 - mu) * rs * sc.y + bi.y;
  float h2 = (v2 - mu) * rs * sc.z + bi.z;
  float h3 = (v3 - mu) * rs * sc.w + bi.w;
  float4 hv = {h0, h1, h2, h3};
  ((float4*)(hf + row * 256))[lane] = hv;
  ushort4 hbv; hbv.x = f2bfu(h0); hbv.y = f2bfu(h1); hbv.z = f2bfu(h2); hbv.w = f2bfu(h3);
  ((ushort4*)(hb + row * 256))[lane] = hbv;
}

// ---------------- MLP layer: out = resid + [relu](x@W + b), f32 + bf16 -------
template <bool RELU>
__global__ __launch_bounds__(256) void k_mlp(
    const u16* __restrict__ xbf, const float* __restrict__ resid,
    const u16* __restrict__ wpack, const float* __restrict__ bias,
    float* __restrict__ outf, u16* __restrict__ outb)
{
  __shared__ u16 At[64][264];
  __shared__ u16 Bt[256 * 40];
  const int tid = threadIdx.x;
  const int lane = tid & 63, w = tid >> 6;
  const int l16 = lane & 15, g = lane >> 4;
  const int r0 = blockIdx.x * 64;

  #pragma unroll
  for (int it = 0; it < 8; ++it) {
    int c = tid + it * 256;
    int r = c >> 5, seg = c & 31;
    int row = r0 + r;
    uint4 v = {0u, 0u, 0u, 0u};
    if (row < NN) v = *(const uint4*)(xbf + (size_t)row * 256 + seg * 8);
    *(uint4*)&At[r][seg * 8] = v;
  }

  f32x4 acc[4][4];
  const f32x4 z = {0.f, 0.f, 0.f, 0.f};
  #pragma unroll
  for (int i = 0; i < 4; ++i)
    #pragma unroll
    for (int q = 0; q < 4; ++q) acc[i][q] = z;

  for (int t = 0; t < 8; ++t) {
    if (t) __syncthreads();
    #pragma unroll
    for (int it = 0; it < 4; ++it) {
      int c = tid + it * 256;
      int n = c >> 2, gg = c & 3;
      *(uint4*)&Bt[n * 40 + gg * 8] = *(const uint4*)(wpack + (t << 13) + (c << 3));
    }
    __syncthreads();
    ABFrag a[4];
    const int kb = (t << 5) + (g << 2);
    #pragma unroll
    for (int mf = 0; mf < 4; ++mf) {
      int m = (mf << 4) + l16;
      a[mf].h[0] = *(const bf16x4*)&At[m][kb];
      a[mf].h[1] = *(const bf16x4*)&At[m][kb + 16];
    }
    #pragma unroll
    for (int q = 0; q < 4; ++q) {
      int n = (w << 6) + (q << 4) + l16;
      bf16x8 b = *(const bf16x8*)&Bt[n * 40 + (g << 3)];
      #pragma unroll
      for (int mf = 0; mf < 4; ++mf)
        acc[mf][q] = __builtin_amdgcn_mfma_f32_16x16x32_bf16(a[mf].v, b, acc[mf][q], 0, 0, 0);
    }
  }

  #pragma unroll
  for (int q = 0; q < 4; ++q) {
    int n = (w << 6) + (q << 4) + l16;
    float bn = bias[n];
    #pragma unroll
    for (int mf = 0; mf < 4; ++mf) {
      #pragma unroll
      for (int r = 0; r < 4; ++r) {
        int m = (mf << 4) + (g << 2) + r;
        int row = r0 + m;
        if (row < NN) {
          float y = acc[mf][q][r] + bn;
          if (RELU) y = fmaxf(y, 0.f);
          float xn = resid[(size_t)row * 256 + n] + y;
          outf[(size_t)row * 256 + n] = xn;
          outb[(size_t)row * 256 + n] = f2bfu(xn);
        }
      }
    }
  }
}

// ---------------- final layer: LN(nodes + x2 + (x2@W2+b2)) -------------------
__global__ __launch_bounds__(256) void k_final(
    const u16* __restrict__ xbf, const float* x2f,
    const float* __restrict__ nodes,
    const u16* __restrict__ wpack, const float* __restrict__ bias,
    const float* __restrict__ lns, const float* __restrict__ lnb,
    float* out)
{
  union SM {
    struct { u16 At[64][264]; u16 Bt[256 * 40]; } s;
    struct { float tb[64][258]; float mu[64]; float rs[64]; } l;
  };
  __shared__ SM sm;

  const int tid = threadIdx.x;
  const int lane = tid & 63, w = tid >> 6;
  const int l16 = lane & 15, g = lane >> 4;
  const int r0 = blockIdx.x * 64;

  #pragma unroll
  for (int it = 0; it < 8; ++it) {
    int c = tid + it * 256;
    int r = c >> 5, seg = c & 31;
    int row = r0 + r;
    uint4 v = {0u, 0u, 0u, 0u};
    if (row < NN) v = *(const uint4*)(xbf + (size_t)row * 256 + seg * 8);
    *(uint4*)&sm.s.At[r][seg * 8] = v;
  }

  f32x4 acc[4][4];
  const f32x4 z = {0.f, 0.f, 0.f, 0.f};
  #pragma unroll
  for (int i = 0; i < 4; ++i)
    #pragma unroll
    for (int q = 0; q < 4; ++q) acc[i][q] = z;

  for (int t = 0; t < 8; ++t) {
    if (t) __syncthreads();
    #pragma unroll
    for (int it = 0; it < 4; ++it) {
      int c = tid + it * 256;
      int n = c >> 2, gg = c & 3;
      *(uint4*)&sm.s.Bt[n * 40 + gg * 8] = *(const uint4*)(wpack + (t << 13) + (c << 3));
    }
    __syncthreads();
    ABFrag a[4];
    const int kb = (t << 5) + (g << 2);
    #pragma unroll
    for (int mf = 0; mf < 4; ++mf) {
      int m = (mf << 4) + l16;
      a[mf].h[0] = *(const bf16x4*)&sm.s.At[m][kb];
      a[mf].h[1] = *(const bf16x4*)&sm.s.At[m][kb + 16];
    }
    #pragma unroll
    for (int q = 0; q < 4; ++q) {
      int n = (w << 6) + (q << 4) + l16;
      bf16x8 b = *(const bf16x8*)&sm.s.Bt[n * 40 + (g << 3)];
      #pragma unroll
      for (int mf = 0; mf < 4; ++mf)
        acc[mf][q] = __builtin_amdgcn_mfma_f32_16x16x32_bf16(a[mf].v, b, acc[mf][q], 0, 0, 0);
    }
  }

  __syncthreads();  // all LDS GEMM reads done before union repurpose

  #pragma unroll
  for (int q = 0; q < 4; ++q) {
    int n = (w << 6) + (q << 4) + l16;
    float bn = bias[n];
    #pragma unroll
    for (int mf = 0; mf < 4; ++mf) {
      #pragma unroll
      for (int r = 0; r < 4; ++r) {
        int m = (mf << 4) + (g << 2) + r;
        int row = r0 + m;
        float tval = 0.f;
        if (row < NN)
          tval = nodes[(size_t)row * 256 + n] + x2f[(size_t)row * 256 + n]
               + acc[mf][q][r] + bn;
        sm.l.tb[m][n] = tval;
      }
    }
  }
  __syncthreads();

  {
    int r = tid >> 2, sub = tid & 3;
    float s = 0.f, s2 = 0.f;
    #pragma unroll
    for (int i = 0; i < 64; ++i) {
      float v = sm.l.tb[r][sub + 4 * i];
      s += v; s2 += v * v;
    }
    s  += __shfl_xor(s, 1);  s  += __shfl_xor(s, 2);
    s2 += __shfl_xor(s2, 1); s2 += __shfl_xor(s2, 2);
    float mu  = s * (1.f / 256.f);
    float var = s2 * (1.f / 256.f) - mu * mu;
    sm.l.mu[r] = mu;
    sm.l.rs[r] = rsqrtf(var + 1e-6f);
  }
  __syncthreads();

  float scl = lns[tid], bia = lnb[tid];
  for (int rr = 0; rr < 64; ++rr) {
    int row = r0 + rr;
    if (row < NN)
      out[(size_t)row * 256 + tid] =
          (sm.l.tb[rr][tid] - sm.l.mu[rr]) * sm.l.rs[rr] * scl + bia;
  }
}

// ---------------------------------------------------------------------------
extern "C" void kernel_launch(void* const* d_in, const int* in_sizes, int n_in,
                              void* d_out, int out_size, void* d_ws, size_t ws_size,
                              hipStream_t stream)
{
  const float* nodes = (const float*)d_in[0];
  const float* edges = (const float*)d_in[1];
  const int* senders = (const int*)d_in[2];
  const int* receivers = (const int*)d_in[3];
  const float* Wmsg = (const float*)d_in[4];
  const float* W0 = (const float*)d_in[5];
  const float* b0 = (const float*)d_in[6];
  const float* W1 = (const float*)d_in[7];
  const float* b1 = (const float*)d_in[8];
  const float* W2 = (const float*)d_in[9];
  const float* b2 = (const float*)d_in[10];
  const float* lnAs = (const float*)d_in[11];
  const float* lnAb = (const float*)d_in[12];
  const float* lnOs = (const float*)d_in[13];
  const float* lnOb = (const float*)d_in[14];
  float* out = (float*)d_out;
  (void)in_sizes; (void)n_in; (void)out_size; (void)ws_size;

  char* w = (char*)d_ws;
  size_t off = 0;
  auto take = [&](size_t b) { void* p = w + off; off += (b + 511) & ~(size_t)511; return p; };

  u16*   nodes_bf = (u16*)take((size_t)NN * 256 * 2);   // bf16 node table
  u16*   wmsg_p   = (u16*)take(320 * 256 * 2);
  u16*   w0_p     = (u16*)take(256 * 256 * 2);
  u16*   w1_p     = (u16*)take(256 * 256 * 2);
  u16*   w2_p     = (u16*)take(256 * 256 * 2);
  float* bufA     = (float*)take((size_t)NN * 256 * 4); // agg, then x1
  u16*   bfA      = (u16*)take((size_t)NN * 256 * 2);   // h_bf, then x2_bf
  u16*   bfB      = (u16*)take((size_t)NN * 256 * 2);   // x1_bf

  hipMemsetAsync(bufA, 0, (size_t)NN * 256 * 4, stream);
  k_cvt<<<(NN * 256 / 4 + 255) / 256, 256, 0, stream>>>(nodes, nodes_bf, NN * 256 / 4);
  k_pack<<<(320 * 256) / 256, 256, 0, stream>>>(Wmsg, wmsg_p, 320);
  k_pack<<<(256 * 256) / 256, 256, 0, stream>>>(W0, w0_p, 256);
  k_pack<<<(256 * 256) / 256, 256, 0, stream>>>(W1, w1_p, 256);
  k_pack<<<(256 * 256) / 256, 256, 0, stream>>>(W2, w2_p, 256);

  k_msg<<<NE / 64, 256, 0, stream>>>(nodes_bf, edges, senders, receivers, wmsg_p, bufA);
  k_ln_aggr<<<NN / 4, 256, 0, stream>>>(bufA, nodes, lnAs, lnAb, out, bfA);

  const int MB = (NN + 63) / 64;
  // layer0: x1 = h + relu(h@W0+b0)         (h_f32 in out, h_bf in bfA)
  k_mlp<true><<<MB, 256, 0, stream>>>(bfA, out, w0_p, b0, bufA, bfB);
  // layer1: x2 = x1 + relu(x1@W1+b1)
  k_mlp<true><<<MB, 256, 0, stream>>>(bfB, bufA, w1_p, b1, out, bfA);
  // layer2 + final LN -> d_out
  k_final<<<MB, 256, 0, stream>>>(bfA, out, nodes, w2_p, b2, lnOs, lnOb, out);
}

// Round 2
// 582.988 us; speedup vs baseline: 1.2508x; 1.2508x over previous
//
#include <hip/hip_runtime.h>

#define NN 50000
#define NE 400000

typedef unsigned short u16;
typedef unsigned int   u32;
typedef __bf16 bf16x4 __attribute__((ext_vector_type(4)));
typedef __bf16 bf16x8 __attribute__((ext_vector_type(8)));
typedef float  f32x4  __attribute__((ext_vector_type(4)));

union ABFrag { bf16x8 v; bf16x4 h[2]; };

__device__ __forceinline__ u16 f2bfu(float f) {
  u32 u = __builtin_bit_cast(u32, f);
  return (u16)((u + 0x7FFFu + ((u >> 16) & 1u)) >> 16);  // RNE f32->bf16
}
__device__ __forceinline__ float bf2f(u16 u) {
  return __builtin_bit_cast(float, (u32)u << 16);
}

// ---------------- f32 -> bf16 bulk convert (vec4) ----------------
__global__ __launch_bounds__(256) void k_cvt(const float* __restrict__ src,
                                             u16* __restrict__ dst, int n4) {
  int i = blockIdx.x * 256 + threadIdx.x;
  if (i >= n4) return;
  float4 f = ((const float4*)src)[i];
  ushort4 o;
  o.x = f2bfu(f.x); o.y = f2bfu(f.y); o.z = f2bfu(f.z); o.w = f2bfu(f.w);
  ((ushort4*)dst)[i] = o;
}

// ---------------- weight pack: W[K][256] f32 -> MFMA-fragment order bf16 ----
__global__ __launch_bounds__(256) void k_pack(const float* __restrict__ W,
                                              u16* __restrict__ P, int K) {
  int idx = blockIdx.x * 256 + threadIdx.x;
  if (idx >= K * 256) return;
  int k = idx >> 8, n = idx & 255;
  int t = k >> 5, kp = k & 31;
  int g = (kp & 15) >> 2;
  int j = (kp & 3) | ((kp >> 4) << 2);
  P[(((t << 8) + n) << 5) + (g << 3) + j] = f2bfu(W[idx]);
}

// ---------------- counting sort of edges by receiver -------------------------
__global__ __launch_bounds__(256) void k_hist(const int* __restrict__ recv,
                                              int* __restrict__ cnt) {
  int i = blockIdx.x * 256 + threadIdx.x;
  if (i < NE) atomicAdd(&cnt[recv[i]], 1);
}

__global__ __launch_bounds__(1024) void k_scan(const int* __restrict__ cnt,
                                               int* __restrict__ offs,
                                               int* __restrict__ cursor) {
  __shared__ int part[1024];
  const int t = threadIdx.x;
  const int C = (NN + 1023) / 1024;  // 49
  int base = t * C;
  int s = 0;
  for (int i = 0; i < C; ++i) {
    int idx = base + i;
    if (idx < NN) s += cnt[idx];
  }
  part[t] = s;
  __syncthreads();
  for (int d = 1; d < 1024; d <<= 1) {
    int x = part[t];
    int y = (t >= d) ? part[t - d] : 0;
    __syncthreads();
    part[t] = x + y;
    __syncthreads();
  }
  int run = part[t] - s;  // exclusive prefix
  for (int i = 0; i < C; ++i) {
    int idx = base + i;
    if (idx < NN) {
      offs[idx] = run;
      cursor[idx] = run;
      run += cnt[idx];
    }
  }
  if (t == 0) offs[NN] = NE;
}

__global__ __launch_bounds__(256) void k_scatter(
    const int* __restrict__ snd, const int* __restrict__ recv,
    int* __restrict__ cursor, int* __restrict__ s_snd, int* __restrict__ s_eid) {
  int e = blockIdx.x * 256 + threadIdx.x;
  if (e < NE) {
    int p = atomicAdd(&cursor[recv[e]], 1);
    s_snd[p] = snd[e];
    s_eid[p] = e;
  }
}

// ---------------- per-node feature aggregation: X[n] = [Σ s_feat, Σ e_feat] --
__global__ __launch_bounds__(256) void k_aggr(
    const u16* __restrict__ nodes_bf, const float* __restrict__ edges,
    const int* __restrict__ offs, const int* __restrict__ s_snd,
    const int* __restrict__ s_eid, u16* __restrict__ X)
{
  const int wid = blockIdx.x * 4 + (threadIdx.x >> 6);  // node id (grid exact)
  const int lane = threadIdx.x & 63;
  const int beg = offs[wid], end = offs[wid + 1];
  float a0 = 0.f, a1 = 0.f, a2 = 0.f, a3 = 0.f, a4 = 0.f;
  for (int j = beg; j < end; ++j) {
    int snd = s_snd[j];
    int eid = s_eid[j];
    ushort4 nv = *(const ushort4*)(nodes_bf + (size_t)snd * 256 + lane * 4);
    float ev = edges[(size_t)eid * 64 + lane];
    a0 += bf2f(nv.x); a1 += bf2f(nv.y); a2 += bf2f(nv.z); a3 += bf2f(nv.w);
    a4 += ev;
  }
  u16* xr = X + (size_t)wid * 320;
  ushort4 o;
  o.x = f2bfu(a0); o.y = f2bfu(a1); o.z = f2bfu(a2); o.w = f2bfu(a3);
  *(ushort4*)(xr + lane * 4) = o;
  xr[256 + lane] = f2bfu(a4);
}

// ---------------- agg GEMM (K=320) + fused relu+resid+LN --------------------
// h = LN(relu(X@Wmsg) + nodes); writes h f32 and h bf16
__global__ __launch_bounds__(256) void k_gemm_ln_aggr(
    const u16* __restrict__ X, const float* __restrict__ nodes,
    const u16* __restrict__ wpack,
    const float* __restrict__ lns, const float* __restrict__ lnb,
    float* __restrict__ hf, u16* __restrict__ hb)
{
  union SM {
    struct { u16 At[64][328]; u16 Bt[256 * 40]; } s;
    struct { float tb[64][258]; float mu[64]; float rs[64]; } l;
  };
  __shared__ SM sm;

  const int tid = threadIdx.x;
  const int lane = tid & 63, w = tid >> 6;
  const int l16 = lane & 15, g = lane >> 4;
  const int r0 = blockIdx.x * 64;

  #pragma unroll
  for (int it = 0; it < 10; ++it) {
    int c = tid + it * 256;  // 2560 chunks of 16B
    int r = c / 40, seg = c - r * 40;
    int row = r0 + r;
    uint4 v = {0u, 0u, 0u, 0u};
    if (row < NN) v = *(const uint4*)(X + (size_t)row * 320 + seg * 8);
    *(uint4*)&sm.s.At[r][seg * 8] = v;
  }

  f32x4 acc[4][4];
  const f32x4 z = {0.f, 0.f, 0.f, 0.f};
  #pragma unroll
  for (int i = 0; i < 4; ++i)
    #pragma unroll
    for (int q = 0; q < 4; ++q) acc[i][q] = z;

  for (int t = 0; t < 10; ++t) {
    if (t) __syncthreads();
    #pragma unroll
    for (int it = 0; it < 4; ++it) {
      int c = tid + it * 256;
      int n = c >> 2, gg = c & 3;
      *(uint4*)&sm.s.Bt[n * 40 + gg * 8] = *(const uint4*)(wpack + (t << 13) + (c << 3));
    }
    __syncthreads();
    ABFrag a[4];
    const int kb = (t << 5) + (g << 2);
    #pragma unroll
    for (int mf = 0; mf < 4; ++mf) {
      int m = (mf << 4) + l16;
      a[mf].h[0] = *(const bf16x4*)&sm.s.At[m][kb];
      a[mf].h[1] = *(const bf16x4*)&sm.s.At[m][kb + 16];
    }
    #pragma unroll
    for (int q = 0; q < 4; ++q) {
      int n = (w << 6) + (q << 4) + l16;
      bf16x8 b = *(const bf16x8*)&sm.s.Bt[n * 40 + (g << 3)];
      #pragma unroll
      for (int mf = 0; mf < 4; ++mf)
        acc[mf][q] = __builtin_amdgcn_mfma_f32_16x16x32_bf16(a[mf].v, b, acc[mf][q], 0, 0, 0);
    }
  }

  __syncthreads();  // GEMM LDS reads done before union repurpose

  #pragma unroll
  for (int q = 0; q < 4; ++q) {
    int n = (w << 6) + (q << 4) + l16;
    #pragma unroll
    for (int mf = 0; mf < 4; ++mf) {
      #pragma unroll
      for (int r = 0; r < 4; ++r) {
        int m = (mf << 4) + (g << 2) + r;
        int row = r0 + m;
        float tval = 0.f;
        if (row < NN)
          tval = fmaxf(acc[mf][q][r], 0.f) + nodes[(size_t)row * 256 + n];
        sm.l.tb[m][n] = tval;
      }
    }
  }
  __syncthreads();

  {
    int r = tid >> 2, sub = tid & 3;
    float s = 0.f, s2 = 0.f;
    #pragma unroll
    for (int i = 0; i < 64; ++i) {
      float v = sm.l.tb[r][sub + 4 * i];
      s += v; s2 += v * v;
    }
    s  += __shfl_xor(s, 1);  s  += __shfl_xor(s, 2);
    s2 += __shfl_xor(s2, 1); s2 += __shfl_xor(s2, 2);
    float mu  = s * (1.f / 256.f);
    float var = s2 * (1.f / 256.f) - mu * mu;
    sm.l.mu[r] = mu;
    sm.l.rs[r] = rsqrtf(var + 1e-6f);
  }
  __syncthreads();

  float scl = lns[tid], bia = lnb[tid];
  for (int rr = 0; rr < 64; ++rr) {
    int row = r0 + rr;
    if (row < NN) {
      float hv = (sm.l.tb[rr][tid] - sm.l.mu[rr]) * sm.l.rs[rr] * scl + bia;
      hf[(size_t)row * 256 + tid] = hv;
      hb[(size_t)row * 256 + tid] = f2bfu(hv);
    }
  }
}

// ---------------- MLP layer: out = resid + [relu](x@W + b), f32 + bf16 -------
template <bool RELU>
__global__ __launch_bounds__(256) void k_mlp(
    const u16* __restrict__ xbf, const float* __restrict__ resid,
    const u16* __restrict__ wpack, const float* __restrict__ bias,
    float* __restrict__ outf, u16* __restrict__ outb)
{
  __shared__ u16 At[64][264];
  __shared__ u16 Bt[256 * 40];
  const int tid = threadIdx.x;
  const int lane = tid & 63, w = tid >> 6;
  const int l16 = lane & 15, g = lane >> 4;
  const int r0 = blockIdx.x * 64;

  #pragma unroll
  for (int it = 0; it < 8; ++it) {
    int c = tid + it * 256;
    int r = c >> 5, seg = c & 31;
    int row = r0 + r;
    uint4 v = {0u, 0u, 0u, 0u};
    if (row < NN) v = *(const uint4*)(xbf + (size_t)row * 256 + seg * 8);
    *(uint4*)&At[r][seg * 8] = v;
  }

  f32x4 acc[4][4];
  const f32x4 z = {0.f, 0.f, 0.f, 0.f};
  #pragma unroll
  for (int i = 0; i < 4; ++i)
    #pragma unroll
    for (int q = 0; q < 4; ++q) acc[i][q] = z;

  for (int t = 0; t < 8; ++t) {
    if (t) __syncthreads();
    #pragma unroll
    for (int it = 0; it < 4; ++it) {
      int c = tid + it * 256;
      int n = c >> 2, gg = c & 3;
      *(uint4*)&Bt[n * 40 + gg * 8] = *(const uint4*)(wpack + (t << 13) + (c << 3));
    }
    __syncthreads();
    ABFrag a[4];
    const int kb = (t << 5) + (g << 2);
    #pragma unroll
    for (int mf = 0; mf < 4; ++mf) {
      int m = (mf << 4) + l16;
      a[mf].h[0] = *(const bf16x4*)&At[m][kb];
      a[mf].h[1] = *(const bf16x4*)&At[m][kb + 16];
    }
    #pragma unroll
    for (int q = 0; q < 4; ++q) {
      int n = (w << 6) + (q << 4) + l16;
      bf16x8 b = *(const bf16x8*)&Bt[n * 40 + (g << 3)];
      #pragma unroll
      for (int mf = 0; mf < 4; ++mf)
        acc[mf][q] = __builtin_amdgcn_mfma_f32_16x16x32_bf16(a[mf].v, b, acc[mf][q], 0, 0, 0);
    }
  }

  #pragma unroll
  for (int q = 0; q < 4; ++q) {
    int n = (w << 6) + (q << 4) + l16;
    float bn = bias[n];
    #pragma unroll
    for (int mf = 0; mf < 4; ++mf) {
      #pragma unroll
      for (int r = 0; r < 4; ++r) {
        int m = (mf << 4) + (g << 2) + r;
        int row = r0 + m;
        if (row < NN) {
          float y = acc[mf][q][r] + bn;
          if (RELU) y = fmaxf(y, 0.f);
          float xn = resid[(size_t)row * 256 + n] + y;
          outf[(size_t)row * 256 + n] = xn;
          outb[(size_t)row * 256 + n] = f2bfu(xn);
        }
      }
    }
  }
}

// ---------------- final layer: LN(nodes + x2 + (x2@W2+b2)) -------------------
__global__ __launch_bounds__(256) void k_final(
    const u16* __restrict__ xbf, const float* x2f,
    const float* __restrict__ nodes,
    const u16* __restrict__ wpack, const float* __restrict__ bias,
    const float* __restrict__ lns, const float* __restrict__ lnb,
    float* out)
{
  union SM {
    struct { u16 At[64][264]; u16 Bt[256 * 40]; } s;
    struct { float tb[64][258]; float mu[64]; float rs[64]; } l;
  };
  __shared__ SM sm;

  const int tid = threadIdx.x;
  const int lane = tid & 63, w = tid >> 6;
  const int l16 = lane & 15, g = lane >> 4;
  const int r0 = blockIdx.x * 64;

  #pragma unroll
  for (int it = 0; it < 8; ++it) {
    int c = tid + it * 256;
    int r = c >> 5, seg = c & 31;
    int row = r0 + r;
    uint4 v = {0u, 0u, 0u, 0u};
    if (row < NN) v = *(const uint4*)(xbf + (size_t)row * 256 + seg * 8);
    *(uint4*)&sm.s.At[r][seg * 8] = v;
  }

  f32x4 acc[4][4];
  const f32x4 z = {0.f, 0.f, 0.f, 0.f};
  #pragma unroll
  for (int i = 0; i < 4; ++i)
    #pragma unroll
    for (int q = 0; q < 4; ++q) acc[i][q] = z;

  for (int t = 0; t < 8; ++t) {
    if (t) __syncthreads();
    #pragma unroll
    for (int it = 0; it < 4; ++it) {
      int c = tid + it * 256;
      int n = c >> 2, gg = c & 3;
      *(uint4*)&sm.s.Bt[n * 40 + gg * 8] = *(const uint4*)(wpack + (t << 13) + (c << 3));
    }
    __syncthreads();
    ABFrag a[4];
    const int kb = (t << 5) + (g << 2);
    #pragma unroll
    for (int mf = 0; mf < 4; ++mf) {
      int m = (mf << 4) + l16;
      a[mf].h[0] = *(const bf16x4*)&sm.s.At[m][kb];
      a[mf].h[1] = *(const bf16x4*)&sm.s.At[m][kb + 16];
    }
    #pragma unroll
    for (int q = 0; q < 4; ++q) {
      int n = (w << 6) + (q << 4) + l16;
      bf16x8 b = *(const bf16x8*)&sm.s.Bt[n * 40 + (g << 3)];
      #pragma unroll
      for (int mf = 0; mf < 4; ++mf)
        acc[mf][q] = __builtin_amdgcn_mfma_f32_16x16x32_bf16(a[mf].v, b, acc[mf][q], 0, 0, 0);
    }
  }

  __syncthreads();  // all LDS GEMM reads done before union repurpose

  #pragma unroll
  for (int q = 0; q < 4; ++q) {
    int n = (w << 6) + (q << 4) + l16;
    float bn = bias[n];
    #pragma unroll
    for (int mf = 0; mf < 4; ++mf) {
      #pragma unroll
      for (int r = 0; r < 4; ++r) {
        int m = (mf << 4) + (g << 2) + r;
        int row = r0 + m;
        float tval = 0.f;
        if (row < NN)
          tval = nodes[(size_t)row * 256 + n] + x2f[(size_t)row * 256 + n]
               + acc[mf][q][r] + bn;
        sm.l.tb[m][n] = tval;
      }
    }
  }
  __syncthreads();

  {
    int r = tid >> 2, sub = tid & 3;
    float s = 0.f, s2 = 0.f;
    #pragma unroll
    for (int i = 0; i < 64; ++i) {
      float v = sm.l.tb[r][sub + 4 * i];
      s += v; s2 += v * v;
    }
    s  += __shfl_xor(s, 1);  s  += __shfl_xor(s, 2);
    s2 += __shfl_xor(s2, 1); s2 += __shfl_xor(s2, 2);
    float mu  = s * (1.f / 256.f);
    float var = s2 * (1.f / 256.f) - mu * mu;
    sm.l.mu[r] = mu;
    sm.l.rs[r] = rsqrtf(var + 1e-6f);
  }
  __syncthreads();

  float scl = lns[tid], bia = lnb[tid];
  for (int rr = 0; rr < 64; ++rr) {
    int row = r0 + rr;
    if (row < NN)
      out[(size_t)row * 256 + tid] =
          (sm.l.tb[rr][tid] - sm.l.mu[rr]) * sm.l.rs[rr] * scl + bia;
  }
}

// ---------------------------------------------------------------------------
extern "C" void kernel_launch(void* const* d_in, const int* in_sizes, int n_in,
                              void* d_out, int out_size, void* d_ws, size_t ws_size,
                              hipStream_t stream)
{
  const float* nodes = (const float*)d_in[0];
  const float* edges = (const float*)d_in[1];
  const int* senders = (const int*)d_in[2];
  const int* receivers = (const int*)d_in[3];
  const float* Wmsg = (const float*)d_in[4];
  const float* W0 = (const float*)d_in[5];
  const float* b0 = (const float*)d_in[6];
  const float* W1 = (const float*)d_in[7];
  const float* b1 = (const float*)d_in[8];
  const float* W2 = (const float*)d_in[9];
  const float* b2 = (const float*)d_in[10];
  const float* lnAs = (const float*)d_in[11];
  const float* lnAb = (const float*)d_in[12];
  const float* lnOs = (const float*)d_in[13];
  const float* lnOb = (const float*)d_in[14];
  float* out = (float*)d_out;
  (void)in_sizes; (void)n_in; (void)out_size; (void)ws_size;

  char* w = (char*)d_ws;
  size_t off = 0;
  auto take = [&](size_t b) { void* p = w + off; off += (b + 511) & ~(size_t)511; return p; };

  u16*   nodes_bf = (u16*)take((size_t)NN * 256 * 2);   // bf16 node table
  u16*   wmsg_p   = (u16*)take(320 * 256 * 2);
  u16*   w0_p     = (u16*)take(256 * 256 * 2);
  u16*   w1_p     = (u16*)take(256 * 256 * 2);
  u16*   w2_p     = (u16*)take(256 * 256 * 2);
  float* bufA     = (float*)take((size_t)NN * 256 * 4); // X (bf16 alias), then x1 f32
  u16*   bfA      = (u16*)take((size_t)NN * 256 * 2);   // h_bf, then x2_bf
  u16*   bfB      = (u16*)take((size_t)NN * 256 * 2);   // x1_bf
  int*   cnt      = (int*)take((size_t)NN * 4);
  int*   offs     = (int*)take((size_t)(NN + 1) * 4);
  int*   cursor   = (int*)take((size_t)NN * 4);
  int*   s_snd    = (int*)take((size_t)NE * 4);
  int*   s_eid    = (int*)take((size_t)NE * 4);
  u16*   X        = (u16*)bufA;                          // [NN][320] bf16, dead before x1

  hipMemsetAsync(cnt, 0, (size_t)NN * 4, stream);
  k_cvt<<<(NN * 256 / 4 + 255) / 256, 256, 0, stream>>>(nodes, nodes_bf, NN * 256 / 4);
  k_pack<<<(320 * 256) / 256, 256, 0, stream>>>(Wmsg, wmsg_p, 320);
  k_pack<<<(256 * 256) / 256, 256, 0, stream>>>(W0, w0_p, 256);
  k_pack<<<(256 * 256) / 256, 256, 0, stream>>>(W1, w1_p, 256);
  k_pack<<<(256 * 256) / 256, 256, 0, stream>>>(W2, w2_p, 256);

  // counting sort by receiver
  k_hist<<<(NE + 255) / 256, 256, 0, stream>>>(receivers, cnt);
  k_scan<<<1, 1024, 0, stream>>>(cnt, offs, cursor);
  k_scatter<<<(NE + 255) / 256, 256, 0, stream>>>(senders, receivers, cursor, s_snd, s_eid);

  // X[n] = [sum of sender features, sum of edge features]
  k_aggr<<<NN / 4, 256, 0, stream>>>(nodes_bf, edges, offs, s_snd, s_eid, X);

  const int MB = (NN + 63) / 64;
  // h = LN(relu(X@Wmsg) + nodes) -> out (f32) + bfA (bf16)
  k_gemm_ln_aggr<<<MB, 256, 0, stream>>>(X, nodes, wmsg_p, lnAs, lnAb, out, bfA);
  // layer0: x1 = h + relu(h@W0+b0)
  k_mlp<true><<<MB, 256, 0, stream>>>(bfA, out, w0_p, b0, bufA, bfB);
  // layer1: x2 = x1 + relu(x1@W1+b1)
  k_mlp<true><<<MB, 256, 0, stream>>>(bfB, bufA, w1_p, b1, out, bfA);
  // layer2 + final LN -> d_out
  k_final<<<MB, 256, 0, stream>>>(bfA, out, nodes, w2_p, b2, lnOs, lnOb, out);
}

// Round 3
// 416.974 us; speedup vs baseline: 1.7488x; 1.3981x over previous
//
#include <hip/hip_runtime.h>

#define NN 50000
#define NE 400000

typedef unsigned short u16;
typedef unsigned int   u32;
typedef __bf16 bf16x4 __attribute__((ext_vector_type(4)));
typedef __bf16 bf16x8 __attribute__((ext_vector_type(8)));
typedef float  f32x4  __attribute__((ext_vector_type(4)));

union ABFrag { bf16x8 v; bf16x4 h[2]; };

__device__ __forceinline__ u16 f2bfu(float f) {
  u32 u = __builtin_bit_cast(u32, f);
  return (u16)((u + 0x7FFFu + ((u >> 16) & 1u)) >> 16);  // RNE f32->bf16
}
__device__ __forceinline__ float bf2f(u16 u) {
  return __builtin_bit_cast(float, (u32)u << 16);
}

// ---------------- f32 -> bf16 bulk convert (vec4) ----------------
__global__ __launch_bounds__(256) void k_cvt(const float* __restrict__ src,
                                             u16* __restrict__ dst, int n4) {
  int i = blockIdx.x * 256 + threadIdx.x;
  if (i >= n4) return;
  float4 f = ((const float4*)src)[i];
  ushort4 o;
  o.x = f2bfu(f.x); o.y = f2bfu(f.y); o.z = f2bfu(f.z); o.w = f2bfu(f.w);
  ((ushort4*)dst)[i] = o;
}

// ---------------- weight pack: W[K][256] f32 -> MFMA-fragment order bf16 ----
__global__ __launch_bounds__(256) void k_pack(const float* __restrict__ W,
                                              u16* __restrict__ P, int K) {
  int idx = blockIdx.x * 256 + threadIdx.x;
  if (idx >= K * 256) return;
  int k = idx >> 8, n = idx & 255;
  int t = k >> 5, kp = k & 31;
  int g = (kp & 15) >> 2;
  int j = (kp & 3) | ((kp >> 4) << 2);
  P[(((t << 8) + n) << 5) + (g << 3) + j] = f2bfu(W[idx]);
}

// ---------------- counting sort of edges by receiver -------------------------
__global__ __launch_bounds__(256) void k_hist(const int* __restrict__ recv,
                                              int* __restrict__ cnt) {
  int i = blockIdx.x * 256 + threadIdx.x;
  if (i < NE) atomicAdd(&cnt[recv[i]], 1);
}

// 3-phase scan: per-block scan -> scan of block sums -> add offsets
__global__ __launch_bounds__(256) void k_scan1(const int* __restrict__ cnt,
                                               int* __restrict__ loc,
                                               int* __restrict__ bsum) {
  __shared__ int sm[256];
  int t = threadIdx.x, i = blockIdx.x * 256 + t;
  int v = (i < NN) ? cnt[i] : 0;
  sm[t] = v;
  __syncthreads();
  #pragma unroll
  for (int d = 1; d < 256; d <<= 1) {
    int x = sm[t];
    int y = (t >= d) ? sm[t - d] : 0;
    __syncthreads();
    sm[t] = x + y;
    __syncthreads();
  }
  if (i < NN) loc[i] = sm[t] - v;           // block-local exclusive
  if (t == 255) bsum[blockIdx.x] = sm[255];
}

__global__ __launch_bounds__(256) void k_scan2(int* __restrict__ bsum,
                                               int* __restrict__ bpre, int nb) {
  __shared__ int sm[256];
  int t = threadIdx.x;
  int v = (t < nb) ? bsum[t] : 0;
  sm[t] = v;
  __syncthreads();
  #pragma unroll
  for (int d = 1; d < 256; d <<= 1) {
    int x = sm[t];
    int y = (t >= d) ? sm[t - d] : 0;
    __syncthreads();
    sm[t] = x + y;
    __syncthreads();
  }
  if (t < nb) bpre[t] = sm[t] - v;
}

__global__ __launch_bounds__(256) void k_scan3(const int* __restrict__ loc,
                                               const int* __restrict__ bpre,
                                               int* __restrict__ offs,
                                               int* __restrict__ cursor) {
  int i = blockIdx.x * 256 + threadIdx.x;
  if (i < NN) {
    int o = loc[i] + bpre[blockIdx.x];
    offs[i] = o;
    cursor[i] = o;
  }
  if (i == NN - 1) offs[NN] = NE;
}

__global__ __launch_bounds__(256) void k_scatter(
    const int* __restrict__ snd, const int* __restrict__ recv,
    int* __restrict__ cursor, int* __restrict__ s_snd, int* __restrict__ s_eid) {
  int e = blockIdx.x * 256 + threadIdx.x;
  if (e < NE) {
    int p = atomicAdd(&cursor[recv[e]], 1);
    s_snd[p] = snd[e];
    s_eid[p] = e;
  }
}

// ---------------- per-node feature aggregation: X[n] = [Σ s_feat, Σ e_feat] --
__global__ __launch_bounds__(256) void k_aggr(
    const u16* __restrict__ nodes_bf, const float* __restrict__ edges,
    const int* __restrict__ offs, const int* __restrict__ s_snd,
    const int* __restrict__ s_eid, u16* __restrict__ X)
{
  const int wid = blockIdx.x * 4 + (threadIdx.x >> 6);  // node id (grid exact)
  const int lane = threadIdx.x & 63;
  const int beg = offs[wid], end = offs[wid + 1];
  float a0 = 0.f, a1 = 0.f, a2 = 0.f, a3 = 0.f, a4 = 0.f;
  for (int j = beg; j < end; ++j) {
    int snd = s_snd[j];
    int eid = s_eid[j];
    ushort4 nv = *(const ushort4*)(nodes_bf + (size_t)snd * 256 + lane * 4);
    float ev = edges[(size_t)eid * 64 + lane];
    a0 += bf2f(nv.x); a1 += bf2f(nv.y); a2 += bf2f(nv.z); a3 += bf2f(nv.w);
    a4 += ev;
  }
  u16* xr = X + (size_t)wid * 320;
  ushort4 o;
  o.x = f2bfu(a0); o.y = f2bfu(a1); o.z = f2bfu(a2); o.w = f2bfu(a3);
  *(ushort4*)(xr + lane * 4) = o;
  xr[256 + lane] = f2bfu(a4);
}

// ---------------- agg GEMM (K=320) + fused relu+resid+LN; h f32 only --------
__global__ __launch_bounds__(256) void k_gemm_ln_aggr(
    const u16* __restrict__ X, const float* __restrict__ nodes,
    const u16* __restrict__ wpack,
    const float* __restrict__ lns, const float* __restrict__ lnb,
    float* __restrict__ hf)
{
  union SM {
    struct { u16 At[64][328]; u16 Bt[256 * 40]; } s;
    struct { float tb[64][258]; float mu[64]; float rs[64]; } l;
  };
  __shared__ SM sm;

  const int tid = threadIdx.x;
  const int lane = tid & 63, w = tid >> 6;
  const int l16 = lane & 15, g = lane >> 4;
  const int r0 = blockIdx.x * 64;

  #pragma unroll
  for (int it = 0; it < 10; ++it) {
    int c = tid + it * 256;  // 2560 chunks of 16B
    int r = c / 40, seg = c - r * 40;
    int row = r0 + r;
    uint4 v = {0u, 0u, 0u, 0u};
    if (row < NN) v = *(const uint4*)(X + (size_t)row * 320 + seg * 8);
    *(uint4*)&sm.s.At[r][seg * 8] = v;
  }

  f32x4 acc[4][4];
  const f32x4 z = {0.f, 0.f, 0.f, 0.f};
  #pragma unroll
  for (int i = 0; i < 4; ++i)
    #pragma unroll
    for (int q = 0; q < 4; ++q) acc[i][q] = z;

  for (int t = 0; t < 10; ++t) {
    if (t) __syncthreads();
    #pragma unroll
    for (int it = 0; it < 4; ++it) {
      int c = tid + it * 256;
      int n = c >> 2, gg = c & 3;
      *(uint4*)&sm.s.Bt[n * 40 + gg * 8] = *(const uint4*)(wpack + (t << 13) + (c << 3));
    }
    __syncthreads();
    ABFrag a[4];
    const int kb = (t << 5) + (g << 2);
    #pragma unroll
    for (int mf = 0; mf < 4; ++mf) {
      int m = (mf << 4) + l16;
      a[mf].h[0] = *(const bf16x4*)&sm.s.At[m][kb];
      a[mf].h[1] = *(const bf16x4*)&sm.s.At[m][kb + 16];
    }
    #pragma unroll
    for (int q = 0; q < 4; ++q) {
      int n = (w << 6) + (q << 4) + l16;
      bf16x8 b = *(const bf16x8*)&sm.s.Bt[n * 40 + (g << 3)];
      #pragma unroll
      for (int mf = 0; mf < 4; ++mf)
        acc[mf][q] = __builtin_amdgcn_mfma_f32_16x16x32_bf16(a[mf].v, b, acc[mf][q], 0, 0, 0);
    }
  }

  __syncthreads();  // GEMM LDS reads done before union repurpose

  #pragma unroll
  for (int q = 0; q < 4; ++q) {
    int n = (w << 6) + (q << 4) + l16;
    #pragma unroll
    for (int mf = 0; mf < 4; ++mf) {
      #pragma unroll
      for (int r = 0; r < 4; ++r) {
        int m = (mf << 4) + (g << 2) + r;
        int row = r0 + m;
        float tval = 0.f;
        if (row < NN)
          tval = fmaxf(acc[mf][q][r], 0.f) + nodes[(size_t)row * 256 + n];
        sm.l.tb[m][n] = tval;
      }
    }
  }
  __syncthreads();

  {
    int r = tid >> 2, sub = tid & 3;
    float s = 0.f, s2 = 0.f;
    #pragma unroll
    for (int i = 0; i < 64; ++i) {
      float v = sm.l.tb[r][sub + 4 * i];
      s += v; s2 += v * v;
    }
    s  += __shfl_xor(s, 1);  s  += __shfl_xor(s, 2);
    s2 += __shfl_xor(s2, 1); s2 += __shfl_xor(s2, 2);
    float mu  = s * (1.f / 256.f);
    float var = s2 * (1.f / 256.f) - mu * mu;
    sm.l.mu[r] = mu;
    sm.l.rs[r] = rsqrtf(var + 1e-6f);
  }
  __syncthreads();

  float scl = lns[tid], bia = lnb[tid];
  for (int rr = 0; rr < 64; ++rr) {
    int row = r0 + rr;
    if (row < NN) {
      float hv = (sm.l.tb[rr][tid] - sm.l.mu[rr]) * sm.l.rs[rr] * scl + bia;
      hf[(size_t)row * 256 + tid] = hv;
    }
  }
}

// ---------------- fused 3-layer MLP + final LN -------------------------------
// x = h; for l in 0,1: x += relu(x@Wl+bl);  out = LN(nodes + x + x@W2+b2)
// residual kept in registers (C-fragment layout); bf16 A staged in LDS per layer
__global__ __launch_bounds__(256, 2) void k_mlp3_ln(
    const float* __restrict__ hf, const float* __restrict__ nodes,
    const u16* __restrict__ w0, const u16* __restrict__ w1,
    const u16* __restrict__ w2,
    const float* __restrict__ b0, const float* __restrict__ b1,
    const float* __restrict__ b2,
    const float* __restrict__ lns, const float* __restrict__ lnb,
    float* __restrict__ out)
{
  __shared__ u16 At[64][264];
  __shared__ u16 Bt[256 * 40];
  __shared__ float red[64][8];   // [row][w*2 + {sum,sumsq}]
  __shared__ float murs[64][2];

  const int tid = threadIdx.x;
  const int lane = tid & 63, w = tid >> 6;
  const int l16 = lane & 15, g = lane >> 4;
  const int r0 = blockIdx.x * 64;

  // stage At (bf16 of h) from f32 hf
  #pragma unroll
  for (int it = 0; it < 8; ++it) {
    int c = tid + it * 256;     // 2048 chunks of 8 elems
    int r = c >> 5, seg = c & 31;
    int row = r0 + r;
    ushort4 o0 = {0, 0, 0, 0}, o1 = {0, 0, 0, 0};
    if (row < NN) {
      const float* src = hf + (size_t)row * 256 + seg * 8;
      float4 f0 = ((const float4*)src)[0];
      float4 f1 = ((const float4*)src)[1];
      o0.x = f2bfu(f0.x); o0.y = f2bfu(f0.y); o0.z = f2bfu(f0.z); o0.w = f2bfu(f0.w);
      o1.x = f2bfu(f1.x); o1.y = f2bfu(f1.y); o1.z = f2bfu(f1.z); o1.w = f2bfu(f1.w);
    }
    *(ushort4*)&At[r][seg * 8]     = o0;
    *(ushort4*)&At[r][seg * 8 + 4] = o1;
  }

  // residual x in registers, C-fragment layout (f32 precision)
  f32x4 res[4][4];
  f32x4 acc[4][4];
  const f32x4 z = {0.f, 0.f, 0.f, 0.f};
  #pragma unroll
  for (int q = 0; q < 4; ++q) {
    int n = (w << 6) + (q << 4) + l16;
    #pragma unroll
    for (int mf = 0; mf < 4; ++mf) {
      acc[mf][q] = z;
      #pragma unroll
      for (int r = 0; r < 4; ++r) {
        int row = r0 + (mf << 4) + (g << 2) + r;
        res[mf][q][r] = (row < NN) ? hf[(size_t)row * 256 + n] : 0.f;
      }
    }
  }

  for (int l = 0; l < 3; ++l) {
    const u16* wp = (l == 0) ? w0 : (l == 1) ? w1 : w2;

    for (int t = 0; t < 8; ++t) {
      __syncthreads();          // At writes (staging/epilogue) + Bt reuse
      #pragma unroll
      for (int it = 0; it < 4; ++it) {
        int c = tid + it * 256;
        int n = c >> 2, gg = c & 3;
        *(uint4*)&Bt[n * 40 + gg * 8] = *(const uint4*)(wp + (t << 13) + (c << 3));
      }
      __syncthreads();
      ABFrag a[4];
      const int kb = (t << 5) + (g << 2);
      #pragma unroll
      for (int mf = 0; mf < 4; ++mf) {
        int m = (mf << 4) + l16;
        a[mf].h[0] = *(const bf16x4*)&At[m][kb];
        a[mf].h[1] = *(const bf16x4*)&At[m][kb + 16];
      }
      #pragma unroll
      for (int q = 0; q < 4; ++q) {
        int n = (w << 6) + (q << 4) + l16;
        bf16x8 b = *(const bf16x8*)&Bt[n * 40 + (g << 3)];
        #pragma unroll
        for (int mf = 0; mf < 4; ++mf)
          acc[mf][q] = __builtin_amdgcn_mfma_f32_16x16x32_bf16(a[mf].v, b, acc[mf][q], 0, 0, 0);
      }
    }

    __syncthreads();            // all At reads done before epilogue overwrites

    if (l < 2) {
      const float* bp = (l == 0) ? b0 : b1;
      #pragma unroll
      for (int q = 0; q < 4; ++q) {
        int n = (w << 6) + (q << 4) + l16;
        float bn = bp[n];
        #pragma unroll
        for (int mf = 0; mf < 4; ++mf) {
          #pragma unroll
          for (int r = 0; r < 4; ++r) {
            int m = (mf << 4) + (g << 2) + r;
            float xn = res[mf][q][r] + fmaxf(acc[mf][q][r] + bn, 0.f);
            res[mf][q][r] = xn;
            At[m][n] = f2bfu(xn);
            acc[mf][q][r] = 0.f;
          }
        }
      }
    } else {
      #pragma unroll
      for (int q = 0; q < 4; ++q) {
        int n = (w << 6) + (q << 4) + l16;
        float bn = b2[n];
        #pragma unroll
        for (int mf = 0; mf < 4; ++mf) {
          #pragma unroll
          for (int r = 0; r < 4; ++r) {
            int row = r0 + (mf << 4) + (g << 2) + r;
            float nv = (row < NN) ? nodes[(size_t)row * 256 + n] : 0.f;
            acc[mf][q][r] = nv + res[mf][q][r] + acc[mf][q][r] + bn;
          }
        }
      }
    }
  }

  // ---- final LayerNorm over acc (pre-LN values), rows in C-layout ----
  #pragma unroll
  for (int mf = 0; mf < 4; ++mf) {
    #pragma unroll
    for (int r = 0; r < 4; ++r) {
      float s = 0.f, s2 = 0.f;
      #pragma unroll
      for (int q = 0; q < 4; ++q) {
        float v = acc[mf][q][r];
        s += v; s2 += v * v;
      }
      #pragma unroll
      for (int mk = 1; mk < 16; mk <<= 1) {
        s  += __shfl_xor(s, mk);
        s2 += __shfl_xor(s2, mk);
      }
      if (l16 == 0) {
        int m = (mf << 4) + (g << 2) + r;
        red[m][w * 2]     = s;
        red[m][w * 2 + 1] = s2;
      }
    }
  }
  __syncthreads();
  if (tid < 64) {
    float s = 0.f, s2 = 0.f;
    #pragma unroll
    for (int wi = 0; wi < 4; ++wi) {
      s  += red[tid][wi * 2];
      s2 += red[tid][wi * 2 + 1];
    }
    float mu  = s * (1.f / 256.f);
    float var = s2 * (1.f / 256.f) - mu * mu;
    murs[tid][0] = mu;
    murs[tid][1] = rsqrtf(var + 1e-6f);
  }
  __syncthreads();

  #pragma unroll
  for (int q = 0; q < 4; ++q) {
    int n = (w << 6) + (q << 4) + l16;
    float scl = lns[n], bia = lnb[n];
    #pragma unroll
    for (int mf = 0; mf < 4; ++mf) {
      #pragma unroll
      for (int r = 0; r < 4; ++r) {
        int m = (mf << 4) + (g << 2) + r;
        int row = r0 + m;
        if (row < NN)
          out[(size_t)row * 256 + n] =
              (acc[mf][q][r] - murs[m][0]) * murs[m][1] * scl + bia;
      }
    }
  }
}

// ---------------------------------------------------------------------------
extern "C" void kernel_launch(void* const* d_in, const int* in_sizes, int n_in,
                              void* d_out, int out_size, void* d_ws, size_t ws_size,
                              hipStream_t stream)
{
  const float* nodes = (const float*)d_in[0];
  const float* edges = (const float*)d_in[1];
  const int* senders = (const int*)d_in[2];
  const int* receivers = (const int*)d_in[3];
  const float* Wmsg = (const float*)d_in[4];
  const float* W0 = (const float*)d_in[5];
  const float* b0 = (const float*)d_in[6];
  const float* W1 = (const float*)d_in[7];
  const float* b1 = (const float*)d_in[8];
  const float* W2 = (const float*)d_in[9];
  const float* b2 = (const float*)d_in[10];
  const float* lnAs = (const float*)d_in[11];
  const float* lnAb = (const float*)d_in[12];
  const float* lnOs = (const float*)d_in[13];
  const float* lnOb = (const float*)d_in[14];
  float* out = (float*)d_out;
  (void)in_sizes; (void)n_in; (void)out_size; (void)ws_size;

  char* w = (char*)d_ws;
  size_t off = 0;
  auto take = [&](size_t b) { void* p = w + off; off += (b + 511) & ~(size_t)511; return p; };

  u16*   nodes_bf = (u16*)take((size_t)NN * 256 * 2);
  u16*   wmsg_p   = (u16*)take(320 * 256 * 2);
  u16*   w0_p     = (u16*)take(256 * 256 * 2);
  u16*   w1_p     = (u16*)take(256 * 256 * 2);
  u16*   w2_p     = (u16*)take(256 * 256 * 2);
  u16*   X        = (u16*)take((size_t)NN * 320 * 2);   // [NN][320] bf16
  float* hbuf     = (float*)take((size_t)NN * 256 * 4); // h f32
  int*   cnt      = (int*)take((size_t)NN * 4);
  int*   loc      = (int*)take((size_t)NN * 4);
  int*   offs     = (int*)take((size_t)(NN + 1) * 4);
  int*   cursor   = (int*)take((size_t)NN * 4);
  int*   s_snd    = (int*)take((size_t)NE * 4);
  int*   s_eid    = (int*)take((size_t)NE * 4);
  int*   bsum     = (int*)take(256 * 4);
  int*   bpre     = (int*)take(256 * 4);

  const int NB = (NN + 255) / 256;  // 196

  hipMemsetAsync(cnt, 0, (size_t)NN * 4, stream);
  k_cvt<<<(NN * 256 / 4 + 255) / 256, 256, 0, stream>>>(nodes, nodes_bf, NN * 256 / 4);
  k_pack<<<(320 * 256) / 256, 256, 0, stream>>>(Wmsg, wmsg_p, 320);
  k_pack<<<(256 * 256) / 256, 256, 0, stream>>>(W0, w0_p, 256);
  k_pack<<<(256 * 256) / 256, 256, 0, stream>>>(W1, w1_p, 256);
  k_pack<<<(256 * 256) / 256, 256, 0, stream>>>(W2, w2_p, 256);

  // counting sort by receiver (3-phase parallel scan)
  k_hist<<<(NE + 255) / 256, 256, 0, stream>>>(receivers, cnt);
  k_scan1<<<NB, 256, 0, stream>>>(cnt, loc, bsum);
  k_scan2<<<1, 256, 0, stream>>>(bsum, bpre, NB);
  k_scan3<<<NB, 256, 0, stream>>>(loc, bpre, offs, cursor);
  k_scatter<<<(NE + 255) / 256, 256, 0, stream>>>(senders, receivers, cursor, s_snd, s_eid);

  // X[n] = [sum of sender features, sum of edge features]
  k_aggr<<<NN / 4, 256, 0, stream>>>(nodes_bf, edges, offs, s_snd, s_eid, X);

  const int MB = (NN + 63) / 64;
  // h = LN(relu(X@Wmsg) + nodes) -> hbuf (f32)
  k_gemm_ln_aggr<<<MB, 256, 0, stream>>>(X, nodes, wmsg_p, lnAs, lnAb, hbuf);
  // fused: out = LN(nodes + x2 + x2@W2+b2), x1/x2 tile-resident
  k_mlp3_ln<<<MB, 256, 0, stream>>>(hbuf, nodes, w0_p, w1_p, w2_p,
                                    b0, b1, b2, lnOs, lnOb, out);
}

// Round 4
// 314.912 us; speedup vs baseline: 2.3156x; 1.3241x over previous
//
#include <hip/hip_runtime.h>

#define NN 50000
#define NE 400000

typedef unsigned short u16;
typedef unsigned int   u32;
typedef __bf16 bf16x4 __attribute__((ext_vector_type(4)));
typedef __bf16 bf16x8 __attribute__((ext_vector_type(8)));
typedef float  f32x4  __attribute__((ext_vector_type(4)));

union ABFrag { bf16x8 v; bf16x4 h[2]; };

__device__ __forceinline__ u16 f2bfu(float f) {
  u32 u = __builtin_bit_cast(u32, f);
  return (u16)((u + 0x7FFFu + ((u >> 16) & 1u)) >> 16);  // RNE f32->bf16
}
__device__ __forceinline__ float bf2f(u16 u) {
  return __builtin_bit_cast(float, (u32)u << 16);
}

// ---------------- f32 -> bf16 bulk convert (vec4) ----------------
__global__ __launch_bounds__(256) void k_cvt(const float* __restrict__ src,
                                             u16* __restrict__ dst, int n4) {
  int i = blockIdx.x * 256 + threadIdx.x;
  if (i >= n4) return;
  float4 f = ((const float4*)src)[i];
  ushort4 o;
  o.x = f2bfu(f.x); o.y = f2bfu(f.y); o.z = f2bfu(f.z); o.w = f2bfu(f.w);
  ((ushort4*)dst)[i] = o;
}

// ---------------- weight pack (all 4 weights in one launch) ------------------
// pack[((t*256+n)*4+g)*8+j] = W[32t + 4g + (j%4) + 16*(j/4)][n]
__device__ __forceinline__ void pack_one(const float* __restrict__ W,
                                         u16* __restrict__ P, int idx) {
  int k = idx >> 8, n = idx & 255;
  int t = k >> 5, kp = k & 31;
  int g = (kp & 15) >> 2;
  int j = (kp & 3) | ((kp >> 4) << 2);
  P[(((t << 8) + n) << 5) + (g << 3) + j] = f2bfu(W[idx]);
}

__global__ __launch_bounds__(256) void k_pack4(
    const float* __restrict__ Wm, const float* __restrict__ W0,
    const float* __restrict__ W1, const float* __restrict__ W2,
    u16* __restrict__ Pm, u16* __restrict__ P0,
    u16* __restrict__ P1, u16* __restrict__ P2) {
  int idx = blockIdx.x * 256 + threadIdx.x;
  const int S0 = 320 * 256, S1 = S0 + 256 * 256, S2 = S1 + 256 * 256, S3 = S2 + 256 * 256;
  if (idx < S0)      pack_one(Wm, Pm, idx);
  else if (idx < S1) pack_one(W0, P0, idx - S0);
  else if (idx < S2) pack_one(W1, P1, idx - S1);
  else if (idx < S3) pack_one(W2, P2, idx - S2);
}

// ---------------- counting sort of edges by receiver -------------------------
__global__ __launch_bounds__(256) void k_hist(const int* __restrict__ recv,
                                              int* __restrict__ cnt) {
  int i = blockIdx.x * 256 + threadIdx.x;
  if (i < NE) atomicAdd(&cnt[recv[i]], 1);
}

__global__ __launch_bounds__(256) void k_scan1(const int* __restrict__ cnt,
                                               int* __restrict__ loc,
                                               int* __restrict__ bsum) {
  __shared__ int sm[256];
  int t = threadIdx.x, i = blockIdx.x * 256 + t;
  int v = (i < NN) ? cnt[i] : 0;
  sm[t] = v;
  __syncthreads();
  #pragma unroll
  for (int d = 1; d < 256; d <<= 1) {
    int x = sm[t];
    int y = (t >= d) ? sm[t - d] : 0;
    __syncthreads();
    sm[t] = x + y;
    __syncthreads();
  }
  if (i < NN) loc[i] = sm[t] - v;
  if (t == 255) bsum[blockIdx.x] = sm[255];
}

__global__ __launch_bounds__(256) void k_scan2(int* __restrict__ bsum,
                                               int* __restrict__ bpre, int nb) {
  __shared__ int sm[256];
  int t = threadIdx.x;
  int v = (t < nb) ? bsum[t] : 0;
  sm[t] = v;
  __syncthreads();
  #pragma unroll
  for (int d = 1; d < 256; d <<= 1) {
    int x = sm[t];
    int y = (t >= d) ? sm[t - d] : 0;
    __syncthreads();
    sm[t] = x + y;
    __syncthreads();
  }
  if (t < nb) bpre[t] = sm[t] - v;
}

__global__ __launch_bounds__(256) void k_scan3(const int* __restrict__ loc,
                                               const int* __restrict__ bpre,
                                               int* __restrict__ offs,
                                               int* __restrict__ cursor) {
  int i = blockIdx.x * 256 + threadIdx.x;
  if (i < NN) {
    int o = loc[i] + bpre[blockIdx.x];
    offs[i] = o;
    cursor[i] = o;
  }
  if (i == NN - 1) offs[NN] = NE;
}

__global__ __launch_bounds__(256) void k_scatter(
    const int* __restrict__ snd, const int* __restrict__ recv,
    int* __restrict__ cursor, int* __restrict__ s_snd, int* __restrict__ s_eid) {
  int e = blockIdx.x * 256 + threadIdx.x;
  if (e < NE) {
    int p = atomicAdd(&cursor[recv[e]], 1);
    s_snd[p] = snd[e];
    s_eid[p] = e;
  }
}

// ---------------- per-node feature aggregation: X[n] = [Σ s_feat, Σ e_feat] --
__global__ __launch_bounds__(256) void k_aggr(
    const u16* __restrict__ nodes_bf, const float* __restrict__ edges,
    const int* __restrict__ offs, const int* __restrict__ s_snd,
    const int* __restrict__ s_eid, u16* __restrict__ X)
{
  const int wid = blockIdx.x * 4 + (threadIdx.x >> 6);
  const int lane = threadIdx.x & 63;
  const int beg = offs[wid], end = offs[wid + 1];
  float a0 = 0.f, a1 = 0.f, a2 = 0.f, a3 = 0.f, a4 = 0.f;
  for (int j = beg; j < end; ++j) {
    int snd = s_snd[j];
    int eid = s_eid[j];
    ushort4 nv = *(const ushort4*)(nodes_bf + (size_t)snd * 256 + lane * 4);
    float ev = edges[(size_t)eid * 64 + lane];
    a0 += bf2f(nv.x); a1 += bf2f(nv.y); a2 += bf2f(nv.z); a3 += bf2f(nv.w);
    a4 += ev;
  }
  u16* xr = X + (size_t)wid * 320;
  ushort4 o;
  o.x = f2bfu(a0); o.y = f2bfu(a1); o.z = f2bfu(a2); o.w = f2bfu(a3);
  *(ushort4*)(xr + lane * 4) = o;
  xr[256 + lane] = f2bfu(a4);
}

// ---------------- fully fused dense chain ------------------------------------
// h  = LN_a(relu(X@Wm) + nodes)             (h kept bf16 in LDS At)
// x += relu(x@W0+b0); x += relu(x@W1+b1)    (residual read back from At)
// out = LN_o(nodes + x + x@W2 + b2)
__global__ __launch_bounds__(256, 2) void k_fused(
    const u16* __restrict__ X, const float* __restrict__ nodes,
    const u16* __restrict__ wm, const u16* __restrict__ w0,
    const u16* __restrict__ w1, const u16* __restrict__ w2,
    const float* __restrict__ b0, const float* __restrict__ b1,
    const float* __restrict__ b2,
    const float* __restrict__ lnAs, const float* __restrict__ lnAb,
    const float* __restrict__ lnOs, const float* __restrict__ lnOb,
    float* __restrict__ out)
{
  __shared__ u16 At[64][328];    // K=320 staging; later holds x (bf16) cols 0..255
  __shared__ u16 Bt[256 * 40];
  __shared__ float red[64][8];
  __shared__ float murs[64][2];

  const int tid = threadIdx.x;
  const int lane = tid & 63, w = tid >> 6;
  const int l16 = lane & 15, g = lane >> 4;
  const int r0 = blockIdx.x * 64;

  // ---- stage X (bf16, K=320) ----
  #pragma unroll
  for (int it = 0; it < 10; ++it) {
    int c = tid + it * 256;
    int r = c / 40, seg = c - r * 40;
    int row = r0 + r;
    uint4 v = {0u, 0u, 0u, 0u};
    if (row < NN) v = *(const uint4*)(X + (size_t)row * 320 + seg * 8);
    *(uint4*)&At[r][seg * 8] = v;
  }

  f32x4 acc[4][4];
  const f32x4 z = {0.f, 0.f, 0.f, 0.f};
  #pragma unroll
  for (int i = 0; i < 4; ++i)
    #pragma unroll
    for (int q = 0; q < 4; ++q) acc[i][q] = z;

  // ---- GEMM: X @ Wmsg (K=320) ----
  for (int t = 0; t < 10; ++t) {
    if (t) __syncthreads();
    #pragma unroll
    for (int it = 0; it < 4; ++it) {
      int c = tid + it * 256;
      int n = c >> 2, gg = c & 3;
      *(uint4*)&Bt[n * 40 + gg * 8] = *(const uint4*)(wm + (t << 13) + (c << 3));
    }
    __syncthreads();
    ABFrag a[4];
    const int kb = (t << 5) + (g << 2);
    #pragma unroll
    for (int mf = 0; mf < 4; ++mf) {
      int m = (mf << 4) + l16;
      a[mf].h[0] = *(const bf16x4*)&At[m][kb];
      a[mf].h[1] = *(const bf16x4*)&At[m][kb + 16];
    }
    #pragma unroll
    for (int q = 0; q < 4; ++q) {
      int n = (w << 6) + (q << 4) + l16;
      bf16x8 b = *(const bf16x8*)&Bt[n * 40 + (g << 3)];
      #pragma unroll
      for (int mf = 0; mf < 4; ++mf)
        acc[mf][q] = __builtin_amdgcn_mfma_f32_16x16x32_bf16(a[mf].v, b, acc[mf][q], 0, 0, 0);
    }
  }
  __syncthreads();  // At reads done

  // ---- aggr epilogue: v = relu(acc) + nodes (in-place in acc) ----
  #pragma unroll
  for (int q = 0; q < 4; ++q) {
    int n = (w << 6) + (q << 4) + l16;
    #pragma unroll
    for (int mf = 0; mf < 4; ++mf) {
      #pragma unroll
      for (int r = 0; r < 4; ++r) {
        int row = r0 + (mf << 4) + (g << 2) + r;
        float nv = (row < NN) ? nodes[(size_t)row * 256 + n] : 0.f;
        acc[mf][q][r] = fmaxf(acc[mf][q][r], 0.f) + nv;
      }
    }
  }
  // ---- LN_a stats (register-side, C-layout) ----
  #pragma unroll
  for (int mf = 0; mf < 4; ++mf) {
    #pragma unroll
    for (int r = 0; r < 4; ++r) {
      float s = 0.f, s2 = 0.f;
      #pragma unroll
      for (int q = 0; q < 4; ++q) {
        float v = acc[mf][q][r];
        s += v; s2 += v * v;
      }
      #pragma unroll
      for (int mk = 1; mk < 16; mk <<= 1) {
        s  += __shfl_xor(s, mk);
        s2 += __shfl_xor(s2, mk);
      }
      if (l16 == 0) {
        int m = (mf << 4) + (g << 2) + r;
        red[m][w * 2]     = s;
        red[m][w * 2 + 1] = s2;
      }
    }
  }
  __syncthreads();
  if (tid < 64) {
    float s = 0.f, s2 = 0.f;
    #pragma unroll
    for (int wi = 0; wi < 4; ++wi) { s += red[tid][wi * 2]; s2 += red[tid][wi * 2 + 1]; }
    float mu  = s * (1.f / 256.f);
    float var = s2 * (1.f / 256.f) - mu * mu;
    murs[tid][0] = mu;
    murs[tid][1] = rsqrtf(var + 1e-6f);
  }
  __syncthreads();
  // ---- h = LN_a(v); store bf16 into At (becomes x and the residual) ----
  #pragma unroll
  for (int q = 0; q < 4; ++q) {
    int n = (w << 6) + (q << 4) + l16;
    float scl = lnAs[n], bia = lnAb[n];
    #pragma unroll
    for (int mf = 0; mf < 4; ++mf) {
      #pragma unroll
      for (int r = 0; r < 4; ++r) {
        int m = (mf << 4) + (g << 2) + r;
        float h = (acc[mf][q][r] - murs[m][0]) * murs[m][1] * scl + bia;
        At[m][n] = f2bfu(h);
        acc[mf][q][r] = 0.f;
      }
    }
  }

  // ---- 3 MLP layers; residual lives in At (bf16) ----
  for (int l = 0; l < 3; ++l) {
    const u16* wp = (l == 0) ? w0 : (l == 1) ? w1 : w2;

    for (int t = 0; t < 8; ++t) {
      __syncthreads();          // At/Bt writes visible, prior reads done
      #pragma unroll
      for (int it = 0; it < 4; ++it) {
        int c = tid + it * 256;
        int n = c >> 2, gg = c & 3;
        *(uint4*)&Bt[n * 40 + gg * 8] = *(const uint4*)(wp + (t << 13) + (c << 3));
      }
      __syncthreads();
      ABFrag a[4];
      const int kb = (t << 5) + (g << 2);
      #pragma unroll
      for (int mf = 0; mf < 4; ++mf) {
        int m = (mf << 4) + l16;
        a[mf].h[0] = *(const bf16x4*)&At[m][kb];
        a[mf].h[1] = *(const bf16x4*)&At[m][kb + 16];
      }
      #pragma unroll
      for (int q = 0; q < 4; ++q) {
        int n = (w << 6) + (q << 4) + l16;
        bf16x8 b = *(const bf16x8*)&Bt[n * 40 + (g << 3)];
        #pragma unroll
        for (int mf = 0; mf < 4; ++mf)
          acc[mf][q] = __builtin_amdgcn_mfma_f32_16x16x32_bf16(a[mf].v, b, acc[mf][q], 0, 0, 0);
      }
    }
    __syncthreads();            // all At A-frag reads done before epilogue

    if (l < 2) {
      const float* bp = (l == 0) ? b0 : b1;
      #pragma unroll
      for (int q = 0; q < 4; ++q) {
        int n = (w << 6) + (q << 4) + l16;
        float bn = bp[n];
        #pragma unroll
        for (int mf = 0; mf < 4; ++mf) {
          #pragma unroll
          for (int r = 0; r < 4; ++r) {
            int m = (mf << 4) + (g << 2) + r;
            float xn = bf2f(At[m][n]) + fmaxf(acc[mf][q][r] + bn, 0.f);
            At[m][n] = f2bfu(xn);        // owner thread: safe read-then-write
            acc[mf][q][r] = 0.f;
            acc[mf][q][r] = fmaxf(acc[mf][q][r], 0.f);  // keep zero (no-op)
            acc[mf][q][r] = 0.f;
          }
        }
      }
    } else {
      #pragma unroll
      for (int q = 0; q < 4; ++q) {
        int n = (w << 6) + (q << 4) + l16;
        float bn = b2[n];
        #pragma unroll
        for (int mf = 0; mf < 4; ++mf) {
          #pragma unroll
          for (int r = 0; r < 4; ++r) {
            int m = (mf << 4) + (g << 2) + r;
            int row = r0 + m;
            float nv = (row < NN) ? nodes[(size_t)row * 256 + n] : 0.f;
            acc[mf][q][r] = nv + bf2f(At[m][n]) + acc[mf][q][r] + bn;
          }
        }
      }
    }
  }

  // ---- final LayerNorm over acc ----
  #pragma unroll
  for (int mf = 0; mf < 4; ++mf) {
    #pragma unroll
    for (int r = 0; r < 4; ++r) {
      float s = 0.f, s2 = 0.f;
      #pragma unroll
      for (int q = 0; q < 4; ++q) {
        float v = acc[mf][q][r];
        s += v; s2 += v * v;
      }
      #pragma unroll
      for (int mk = 1; mk < 16; mk <<= 1) {
        s  += __shfl_xor(s, mk);
        s2 += __shfl_xor(s2, mk);
      }
      if (l16 == 0) {
        int m = (mf << 4) + (g << 2) + r;
        red[m][w * 2]     = s;
        red[m][w * 2 + 1] = s2;
      }
    }
  }
  __syncthreads();
  if (tid < 64) {
    float s = 0.f, s2 = 0.f;
    #pragma unroll
    for (int wi = 0; wi < 4; ++wi) { s += red[tid][wi * 2]; s2 += red[tid][wi * 2 + 1]; }
    float mu  = s * (1.f / 256.f);
    float var = s2 * (1.f / 256.f) - mu * mu;
    murs[tid][0] = mu;
    murs[tid][1] = rsqrtf(var + 1e-6f);
  }
  __syncthreads();

  #pragma unroll
  for (int q = 0; q < 4; ++q) {
    int n = (w << 6) + (q << 4) + l16;
    float scl = lnOs[n], bia = lnOb[n];
    #pragma unroll
    for (int mf = 0; mf < 4; ++mf) {
      #pragma unroll
      for (int r = 0; r < 4; ++r) {
        int m = (mf << 4) + (g << 2) + r;
        int row = r0 + m;
        if (row < NN)
          out[(size_t)row * 256 + n] =
              (acc[mf][q][r] - murs[m][0]) * murs[m][1] * scl + bia;
      }
    }
  }
}

// ---------------------------------------------------------------------------
extern "C" void kernel_launch(void* const* d_in, const int* in_sizes, int n_in,
                              void* d_out, int out_size, void* d_ws, size_t ws_size,
                              hipStream_t stream)
{
  const float* nodes = (const float*)d_in[0];
  const float* edges = (const float*)d_in[1];
  const int* senders = (const int*)d_in[2];
  const int* receivers = (const int*)d_in[3];
  const float* Wmsg = (const float*)d_in[4];
  const float* W0 = (const float*)d_in[5];
  const float* b0 = (const float*)d_in[6];
  const float* W1 = (const float*)d_in[7];
  const float* b1 = (const float*)d_in[8];
  const float* W2 = (const float*)d_in[9];
  const float* b2 = (const float*)d_in[10];
  const float* lnAs = (const float*)d_in[11];
  const float* lnAb = (const float*)d_in[12];
  const float* lnOs = (const float*)d_in[13];
  const float* lnOb = (const float*)d_in[14];
  float* out = (float*)d_out;
  (void)in_sizes; (void)n_in; (void)out_size; (void)ws_size;

  char* w = (char*)d_ws;
  size_t off = 0;
  auto take = [&](size_t b) { void* p = w + off; off += (b + 511) & ~(size_t)511; return p; };

  u16*   nodes_bf = (u16*)take((size_t)NN * 256 * 2);
  u16*   wmsg_p   = (u16*)take(320 * 256 * 2);
  u16*   w0_p     = (u16*)take(256 * 256 * 2);
  u16*   w1_p     = (u16*)take(256 * 256 * 2);
  u16*   w2_p     = (u16*)take(256 * 256 * 2);
  u16*   X        = (u16*)take((size_t)NN * 320 * 2);
  int*   cnt      = (int*)take((size_t)NN * 4);
  int*   loc      = (int*)take((size_t)NN * 4);
  int*   offs     = (int*)take((size_t)(NN + 1) * 4);
  int*   cursor   = (int*)take((size_t)NN * 4);
  int*   s_snd    = (int*)take((size_t)NE * 4);
  int*   s_eid    = (int*)take((size_t)NE * 4);
  int*   bsum     = (int*)take(256 * 4);
  int*   bpre     = (int*)take(256 * 4);

  const int NB = (NN + 255) / 256;  // 196

  hipMemsetAsync(cnt, 0, (size_t)NN * 4, stream);
  k_cvt<<<(NN * 256 / 4 + 255) / 256, 256, 0, stream>>>(nodes, nodes_bf, NN * 256 / 4);
  k_pack4<<<(320 * 256 + 3 * 256 * 256) / 256, 256, 0, stream>>>(
      Wmsg, W0, W1, W2, wmsg_p, w0_p, w1_p, w2_p);

  k_hist<<<(NE + 255) / 256, 256, 0, stream>>>(receivers, cnt);
  k_scan1<<<NB, 256, 0, stream>>>(cnt, loc, bsum);
  k_scan2<<<1, 256, 0, stream>>>(bsum, bpre, NB);
  k_scan3<<<NB, 256, 0, stream>>>(loc, bpre, offs, cursor);
  k_scatter<<<(NE + 255) / 256, 256, 0, stream>>>(senders, receivers, cursor, s_snd, s_eid);

  k_aggr<<<NN / 4, 256, 0, stream>>>(nodes_bf, edges, offs, s_snd, s_eid, X);

  const int MB = (NN + 63) / 64;
  k_fused<<<MB, 256, 0, stream>>>(X, nodes, wmsg_p, w0_p, w1_p, w2_p,
                                  b0, b1, b2, lnAs, lnAb, lnOs, lnOb, out);
}